// Round 5
// baseline (364.369 us; speedup 1.0000x reference)
//
#include <hip/hip_runtime.h>

// ---- problem constants ----
#define BB 2
#define SS 1024
#define HIDDEN 2880
#define NH 64
#define NKV 8
#define HD 64
#define M_TOK 2048          // B*S
#define NQ 4096             // NH*HD
#define NKVD 512            // NKV*HD
#define NQKV 5120           // NQ + 2*NKVD
#define NOUT 2880
#define NOUT_PAD 3072       // 12*256

typedef __attribute__((ext_vector_type(8))) short short8;
typedef __attribute__((ext_vector_type(4))) float f32x4;

__device__ __forceinline__ unsigned short f2b(float x) {
  union { float f; unsigned u; } v; v.f = x;
  unsigned r = (v.u + 0x7FFFu + ((v.u >> 16) & 1u)) >> 16;
  return (unsigned short)r;
}

__device__ __forceinline__ void gload16(const void* g, void* l) {
  __builtin_amdgcn_global_load_lds(
      (const __attribute__((address_space(1))) void*)g,
      (__attribute__((address_space(3))) void*)l, 16, 0, 0);
}

#define BAR()  asm volatile("s_barrier" ::: "memory")
#define VMC(n) asm volatile("s_waitcnt vmcnt(" #n ")" ::: "memory")

// ---- cast x (fp32 -> bf16), vectorized ----
__global__ __launch_bounds__(256) void cast_x_kernel(const float* __restrict__ in,
                                                     unsigned short* __restrict__ out,
                                                     int n4) {
  int idx = blockIdx.x * 256 + threadIdx.x;
  if (idx >= n4) return;
  float4 v = ((const float4*)in)[idx];
  ushort4 o;
  o.x = f2b(v.x); o.y = f2b(v.y); o.z = f2b(v.z); o.w = f2b(v.w);
  ((ushort4*)out)[idx] = o;
}

// ---- transpose + cast: out[n*K + k] = (bf16) in[k*ldin + n] ----
__global__ __launch_bounds__(256) void transpose_cast(const float* __restrict__ in,
                                                      long ldin,
                                                      unsigned short* __restrict__ out,
                                                      int K, int N) {
  __shared__ float t[32][33];
  const int n0 = blockIdx.x * 32, k0 = blockIdx.y * 32;
  const int tx = threadIdx.x, ty = threadIdx.y;
#pragma unroll
  for (int i = 0; i < 4; ++i) {
    int k = k0 + ty + i * 8;
    int n = n0 + tx;
    t[ty + i * 8][tx] = (n < N) ? in[(long)k * ldin + n] : 0.f;
  }
  __syncthreads();
#pragma unroll
  for (int i = 0; i < 4; ++i) {
    int n = n0 + ty + i * 8;
    int k = k0 + tx;
    out[(long)n * K + k] = f2b(t[tx][ty + i * 8]);
  }
}

// ---- RoPE cos/sin table ----
__global__ __launch_bounds__(256) void rope_table(const int* __restrict__ pos,
                                                  float* __restrict__ ct,
                                                  float* __restrict__ st) {
  int tid = blockIdx.x * 256 + threadIdx.x;   // < 2048*32
  int t = tid >> 5, i = tid & 31;
  float p = (float)pos[t];
  float f = p * expf(-(float)i * (11.918390573078392f / 32.f));
  ct[tid] = cosf(f);
  st[tid] = sinf(f);
}

// ---- RoPE + pack q (pre-scaled by 1/8) ----
__global__ __launch_bounds__(256) void rope_q_pack(const float* __restrict__ qkvf,
                                                   const float* __restrict__ ct,
                                                   const float* __restrict__ st,
                                                   unsigned short* __restrict__ qb) {
  int tid = blockIdx.x * 256 + threadIdx.x;   // < 2048*64*32
  int i = tid & 31;
  int h = (tid >> 5) & 63;
  int t = tid >> 11;
  const float* src = qkvf + (size_t)t * NQKV + h * 64;
  float x1 = src[i], x2 = src[i + 32];
  float c = ct[t * 32 + i], s = st[t * 32 + i];
  int b = t >> 10, sidx = t & 1023;
  unsigned short* dst = qb + (((size_t)(b * NH + h)) * SS + sidx) * HD;
  dst[i]      = f2b((x1 * c - x2 * s) * 0.125f);
  dst[i + 32] = f2b((x1 * s + x2 * c) * 0.125f);
}

// ---- RoPE + pack k ----
__global__ __launch_bounds__(256) void rope_k_pack(const float* __restrict__ qkvf,
                                                   const float* __restrict__ ct,
                                                   const float* __restrict__ st,
                                                   unsigned short* __restrict__ kb) {
  int tid = blockIdx.x * 256 + threadIdx.x;   // < 2048*8*32
  int i = tid & 31;
  int h = (tid >> 5) & 7;
  int t = tid >> 8;
  const float* src = qkvf + (size_t)t * NQKV + NQ + h * 64;
  float x1 = src[i], x2 = src[i + 32];
  float c = ct[t * 32 + i], s = st[t * 32 + i];
  int b = t >> 10, sidx = t & 1023;
  unsigned short* dst = kb + (((size_t)(b * NKV + h)) * SS + sidx) * HD;
  dst[i]      = f2b(x1 * c - x2 * s);
  dst[i + 32] = f2b(x1 * s + x2 * c);
}

// ==== GEMM 256x256, BK=64, 8 waves, counted-vmcnt 4-phase, race-free ====
// C = A_bf16[M][lda-rows] x Bt_bf16[N][lda]^T over Kloop cols starting at z*Kloop.
// grid z (optional split-K) writes C0 (z=0) or C1 (z=1), ldc cols.
// LDS: A 2x32KB + B 2x32KB. Stage halves == compute halves:
//   quadrant mh reads A rows mh*128+wr*64+mq*16+m16 (wr=w>>2)
//   quadrant nh reads B rows nh*128+wc*32+nf*16+m16 (wc=w&3)
// Stage order per tile: A0,B0 (ph0) -> B1 (ph1) -> A1 (ph2); all into buf^1.
// Waits: ph0-end vmcnt(6) [B1 ready], ph1-end vmcnt(6) [A1 ready],
//        ph3-end vmcnt(4) [next A0,B0 ready]; tail tile: 2/0/-.
__global__ __launch_bounds__(512, 2) void gemm256(const unsigned short* __restrict__ A,
                                                  const unsigned short* __restrict__ Bt,
                                                  float* __restrict__ C0,
                                                  float* __restrict__ C1,
                                                  int lda, int Kloop, int ldc, int Nvalid) {
  __shared__ short8 ldsA[2 * 2048];   // 2 bufs x 32KB
  __shared__ short8 ldsB[2 * 2048];
  char* lAc = (char*)ldsA;
  char* lBc = (char*)ldsB;
  const int tid = threadIdx.x;
  const int lane = tid & 63;
  const int w = tid >> 6;
  const int m16 = lane & 15, g4 = lane >> 4;
  const int wr = w >> 2;              // 0..1  (M wave-row)
  const int wc = w & 3;               // 0..3  (N wave-col)
  const int bm = blockIdx.y * 256, bn = blockIdx.x * 256;
  const int z = blockIdx.z;
  float* __restrict__ Cw = z ? C1 : C0;
  const size_t strAb = (size_t)lda * 2;            // row stride bytes
  const size_t koffb = (size_t)z * Kloop * 2;      // split-K byte offset
  const char* gAc = (const char*)A;
  const char* gBc = (const char*)Bt;

  // staging: 512 threads x 16B = 8KB = 64 rows x 128B per gload issue
  const int srow = tid >> 3;                                   // 0..63
  const int scolb = ((tid & 7) * 16) ^ ((srow & 7) << 4);      // inverse-swizzled src col
  const int sdst = w * 1024;                                   // wave-uniform dest

  auto stA = [&](int buf, int half, int kt) {
    const char* src = gAc + (size_t)(bm + half * 128 + srow) * strAb + koffb + (size_t)kt * 128 + scolb;
    char* dst = lAc + buf * 32768 + half * 16384 + sdst;
    gload16(src, dst);
    gload16(src + 64 * strAb, dst + 8192);
  };
  auto stB = [&](int buf, int half, int kt) {
    const char* src = gBc + (size_t)(bn + half * 128 + srow) * strAb + koffb + (size_t)kt * 128 + scolb;
    char* dst = lBc + buf * 32768 + half * 16384 + sdst;
    gload16(src, dst);
    gload16(src + 64 * strAb, dst + 8192);
  };

  // fragment reads (swizzled): global(row, kb) lives at LDS(row, kb ^ ((row&7)<<4))
  const int swz = (m16 & 7) << 4;
  const int kc0 = (g4 * 16) ^ swz;
  const int kc1 = (64 + g4 * 16) ^ swz;

  f32x4 acc[8][4];
#pragma unroll
  for (int i = 0; i < 8; ++i)
#pragma unroll
    for (int j = 0; j < 4; ++j) acc[i][j] = (f32x4){0.f, 0.f, 0.f, 0.f};
  short8 afr[4][2], bfr[2][2];

#define LOAD_A(bo, mh) { _Pragma("unroll") for (int mq = 0; mq < 4; ++mq) {                     \
    const int row = (mh) * 128 + wr * 64 + mq * 16 + m16;                                       \
    afr[mq][0] = *(const short8*)(lAc + (bo) + row * 128 + kc0);                                \
    afr[mq][1] = *(const short8*)(lAc + (bo) + row * 128 + kc1); } }
#define LOAD_B(bo, nh) { _Pragma("unroll") for (int nf = 0; nf < 2; ++nf) {                     \
    const int row = (nh) * 128 + wc * 32 + nf * 16 + m16;                                       \
    bfr[nf][0] = *(const short8*)(lBc + (bo) + row * 128 + kc0);                                \
    bfr[nf][1] = *(const short8*)(lBc + (bo) + row * 128 + kc1); } }
#define MFMA_Q(mh, nh) { __builtin_amdgcn_s_setprio(1);                                         \
  _Pragma("unroll") for (int mq = 0; mq < 4; ++mq)                                              \
  _Pragma("unroll") for (int nf = 0; nf < 2; ++nf) {                                            \
    acc[(mh)*4+mq][(nh)*2+nf] = __builtin_amdgcn_mfma_f32_16x16x32_bf16(                        \
        afr[mq][0], bfr[nf][0], acc[(mh)*4+mq][(nh)*2+nf], 0, 0, 0);                            \
    acc[(mh)*4+mq][(nh)*2+nf] = __builtin_amdgcn_mfma_f32_16x16x32_bf16(                        \
        afr[mq][1], bfr[nf][1], acc[(mh)*4+mq][(nh)*2+nf], 0, 0, 0); }                          \
  __builtin_amdgcn_s_setprio(0); }

  const int NT = Kloop >> 6;
  // prologue: tile0 in FIFO order A0,B0,B1,A1 (8 loads); A0,B0 ready -> enter
  stA(0, 0, 0); stB(0, 0, 0); stB(0, 1, 0); stA(0, 1, 0);
  VMC(4);
  BAR();

  for (int t = 0; t < NT; ++t) {
    const int buf = t & 1;
    const int bo = buf * 32768;
    const int nb = buf ^ 1;
    const bool more = (t + 1 < NT);
    // ph0: stage A0',B0' ; compute (0,0)
    if (more) { stA(nb, 0, t + 1); stB(nb, 0, t + 1); }
    LOAD_A(bo, 0);
    LOAD_B(bo, 0);
    MFMA_Q(0, 0);
    if (more) { VMC(6); } else { VMC(2); }   // B1(t) landed
    BAR();
    // ph1: stage B1' ; compute (0,1)
    if (more) stB(nb, 1, t + 1);
    LOAD_B(bo, 1);
    MFMA_Q(0, 1);
    if (more) { VMC(6); } else { VMC(0); }   // A1(t) landed
    BAR();
    // ph2: stage A1' ; compute (1,1)
    if (more) stA(nb, 1, t + 1);
    LOAD_A(bo, 1);
    MFMA_Q(1, 1);
    BAR();
    // ph3: compute (1,0) (B0 re-read)
    LOAD_B(bo, 0);
    MFMA_Q(1, 0);
    if (more) { VMC(4); }                    // A0',B0' landed
    BAR();
  }
#undef LOAD_A
#undef LOAD_B
#undef MFMA_Q

  // epilogue: row = bm + mh*128 + wr*64 + mq*16 + g4*4 + r ; col = bn + nh*128 + wc*32 + nf*16 + m16
#pragma unroll
  for (int mi = 0; mi < 8; ++mi) {
    const int mh = mi >> 2, mq = mi & 3;
    const size_t row = bm + mh * 128 + wr * 64 + mq * 16 + g4 * 4;
#pragma unroll
    for (int ni = 0; ni < 4; ++ni) {
      const int nh = ni >> 1, nf = ni & 1;
      const int col = bn + nh * 128 + wc * 32 + nf * 16 + m16;
      if (col < Nvalid) {
#pragma unroll
        for (int r = 0; r < 4; ++r)
          Cw[(row + r) * (size_t)ldc + col] = acc[mi][ni][r];
      }
    }
  }
}

// ---- split-K reduce: out[2048][2880] = p0 + p1 (both [2048][3072]) ----
__global__ __launch_bounds__(256) void reduce_wo(const float* __restrict__ p0,
                                                 const float* __restrict__ p1,
                                                 float* __restrict__ out) {
  int idx = blockIdx.x * 256 + threadIdx.x;   // < 2048*720
  int row = idx / 720, c4 = idx - row * 720;
  const float4 a = *(const float4*)(p0 + (size_t)row * 3072 + c4 * 4);
  const float4 b = *(const float4*)(p1 + (size_t)row * 3072 + c4 * 4);
  float4 o;
  o.x = a.x + b.x; o.y = a.y + b.y; o.z = a.z + b.z; o.w = a.w + b.w;
  *(float4*)(out + (size_t)row * 2880 + c4 * 4) = o;
}

// ---- flash attention (unchanged, validated R2/R3) ----
__global__ __launch_bounds__(512) void attn_fwd(const unsigned short* __restrict__ qb,
                                                const unsigned short* __restrict__ kb,
                                                const unsigned short* __restrict__ vtb,
                                                unsigned short* __restrict__ ao) {
  __shared__ unsigned short kB[2][64 * 64];
  __shared__ unsigned short vB[2][64 * 64];
  __shared__ unsigned short pB[8][32 * 64];
  const int tid = threadIdx.x, lane = tid & 63, w = tid >> 6;
  const int qblk = blockIdx.x;
  const int bh = blockIdx.y;
  const int b = bh >> 6, h = bh & 63, hkv = h >> 3;
  const int m16 = lane & 15, g4 = lane >> 4;
  const int rbase = qblk * 256 + w * 32;

  const unsigned short* qp =
      qb + (((size_t)(b * NH + h)) * SS + rbase + m16) * HD + g4 * 8;
  const short8 q00 = *(const short8*)(qp);
  const short8 q01 = *(const short8*)(qp + 32);
  const short8 q10 = *(const short8*)(qp + 16 * HD);
  const short8 q11 = *(const short8*)(qp + 16 * HD + 32);

  const char* kbp = (const char*)(kb + ((size_t)(b * NKV + hkv)) * SS * HD);
  const char* vbp = (const char*)(vtb + ((size_t)(b * NKV + hkv)) * HD * SS);

  const int lrow = lane >> 3;
  const int lcolb = ((lane & 7) * 16) ^ ((lrow & 7) << 4);
  unsigned short* kDst0 = &kB[0][w * 512];
  unsigned short* kDst1 = &kB[1][w * 512];
  unsigned short* vDst0 = &vB[0][w * 512];
  unsigned short* vDst1 = &vB[1][w * 512];
  const size_t kRowOff = (size_t)(w * 8 + lrow) * 128 + lcolb;
  const size_t vRowOff = (size_t)(w * 8 + lrow) * 2048 + lcolb;

  const short8 ones = {(short)0x3F80, (short)0x3F80, (short)0x3F80, (short)0x3F80,
                       (short)0x3F80, (short)0x3F80, (short)0x3F80, (short)0x3F80};

  f32x4 o0[4], o1[4];
#pragma unroll
  for (int n = 0; n < 4; ++n) { o0[n] = (f32x4){0,0,0,0}; o1[n] = (f32x4){0,0,0,0}; }
  f32x4 lacc0 = (f32x4){0,0,0,0}, lacc1 = (f32x4){0,0,0,0};
  float mrow0[4] = {-1e30f,-1e30f,-1e30f,-1e30f};
  float mrow1[4] = {-1e30f,-1e30f,-1e30f,-1e30f};

  char* pw = (char*)pB[w];
  const int swz_m = (m16 & 7) << 4;
  const int nt = (qblk + 1) * 4;

  gload16(kbp + kRowOff, kDst0);
  gload16(vbp + vRowOff, vDst0);
  __syncthreads();

  for (int t = 0; t < nt; ++t) {
    const int k0 = t * 64;
    const char* kLds = (const char*)kB[t & 1];
    const char* vLds = (const char*)vB[t & 1];
    if (t + 1 < nt) {
      if (t & 1) { gload16(kbp + (size_t)(t + 1) * 8192 + kRowOff, kDst0);
                   gload16(vbp + (size_t)(t + 1) * 128  + vRowOff, vDst0); }
      else       { gload16(kbp + (size_t)(t + 1) * 8192 + kRowOff, kDst1);
                   gload16(vbp + (size_t)(t + 1) * 128  + vRowOff, vDst1); }
    }
    if (k0 < rbase + 32) {
      short8 kf0[4], kf1[4];
#pragma unroll
      for (int kf = 0; kf < 4; ++kf) {
        const int rb = (kf * 16 + m16) * 128;
        kf0[kf] = *(const short8*)(kLds + ((rb + g4 * 16) ^ swz_m));
        kf1[kf] = *(const short8*)(kLds + ((rb + 64 + g4 * 16) ^ swz_m));
      }
      f32x4 s0[4], s1[4];
      __builtin_amdgcn_s_setprio(1);
#pragma unroll
      for (int kf = 0; kf < 4; ++kf) {
        f32x4 z = (f32x4){0,0,0,0};
        z = __builtin_amdgcn_mfma_f32_16x16x32_bf16(q00, kf0[kf], z, 0, 0, 0);
        z = __builtin_amdgcn_mfma_f32_16x16x32_bf16(q01, kf1[kf], z, 0, 0, 0);
        s0[kf] = z;
        f32x4 z2 = (f32x4){0,0,0,0};
        z2 = __builtin_amdgcn_mfma_f32_16x16x32_bf16(q10, kf0[kf], z2, 0, 0, 0);
        z2 = __builtin_amdgcn_mfma_f32_16x16x32_bf16(q11, kf1[kf], z2, 0, 0, 0);
        s1[kf] = z2;
      }
      __builtin_amdgcn_s_setprio(0);
      if (k0 + 63 >= rbase) {
#pragma unroll
        for (int kf = 0; kf < 4; ++kf)
#pragma unroll
          for (int r = 0; r < 4; ++r) {
            const int col = k0 + kf * 16 + m16;
            if (col > rbase + g4 * 4 + r)      s0[kf][r] = -1e30f;
            if (col > rbase + 16 + g4 * 4 + r) s1[kf][r] = -1e30f;
          }
      }
      int grow = 0;
#pragma unroll
      for (int kf = 0; kf < 4; ++kf)
#pragma unroll
        for (int r = 0; r < 4; ++r) {
          grow |= (s0[kf][r] > mrow0[r] + 8.f);
          grow |= (s1[kf][r] > mrow1[r] + 8.f);
        }
      if (__any(grow)) {
        float mx0[4], mx1[4];
#pragma unroll
        for (int r = 0; r < 4; ++r) {
          mx0[r] = fmaxf(fmaxf(s0[0][r], s0[1][r]), fmaxf(s0[2][r], s0[3][r]));
          mx1[r] = fmaxf(fmaxf(s1[0][r], s1[1][r]), fmaxf(s1[2][r], s1[3][r]));
        }
#pragma unroll
        for (int off = 1; off <= 8; off <<= 1)
#pragma unroll
          for (int r = 0; r < 4; ++r) {
            mx0[r] = fmaxf(mx0[r], __shfl_xor(mx0[r], off));
            mx1[r] = fmaxf(mx1[r], __shfl_xor(mx1[r], off));
          }
#pragma unroll
        for (int r = 0; r < 4; ++r) {
          float mn0 = fmaxf(mrow0[r], mx0[r]);
          float sc0 = __expf(mrow0[r] - mn0);
          mrow0[r] = mn0; lacc0[r] *= sc0;
          float mn1 = fmaxf(mrow1[r], mx1[r]);
          float sc1 = __expf(mrow1[r] - mn1);
          mrow1[r] = mn1; lacc1[r] *= sc1;
#pragma unroll
          for (int n = 0; n < 4; ++n) { o0[n][r] *= sc0; o1[n][r] *= sc1; }
        }
      }
#pragma unroll
      for (int kf = 0; kf < 4; ++kf)
#pragma unroll
        for (int r = 0; r < 4; ++r) {
          const int colb = (kf * 16 + m16) * 2;
          int row = g4 * 4 + r;
          *(unsigned short*)(pw + ((row * 128 + colb) ^ ((row & 7) << 4))) =
              f2b(__expf(s0[kf][r] - mrow0[r]));
          row += 16;
          *(unsigned short*)(pw + ((row * 128 + colb) ^ ((row & 7) << 4))) =
              f2b(__expf(s1[kf][r] - mrow1[r]));
        }
      const int prb0 = m16 * 128, prb1 = (16 + m16) * 128;
      short8 pf00 = *(const short8*)(pw + ((prb0 + g4 * 16) ^ swz_m));
      short8 pf01 = *(const short8*)(pw + ((prb0 + 64 + g4 * 16) ^ swz_m));
      short8 pf10 = *(const short8*)(pw + ((prb1 + g4 * 16) ^ swz_m));
      short8 pf11 = *(const short8*)(pw + ((prb1 + 64 + g4 * 16) ^ swz_m));
      __builtin_amdgcn_s_setprio(1);
      lacc0 = __builtin_amdgcn_mfma_f32_16x16x32_bf16(pf00, ones, lacc0, 0, 0, 0);
      lacc0 = __builtin_amdgcn_mfma_f32_16x16x32_bf16(pf01, ones, lacc0, 0, 0, 0);
      lacc1 = __builtin_amdgcn_mfma_f32_16x16x32_bf16(pf10, ones, lacc1, 0, 0, 0);
      lacc1 = __builtin_amdgcn_mfma_f32_16x16x32_bf16(pf11, ones, lacc1, 0, 0, 0);
#pragma unroll
      for (int n = 0; n < 4; ++n) {
        const int rb = (n * 16 + m16) * 128;
        short8 vf0 = *(const short8*)(vLds + ((rb + g4 * 16) ^ swz_m));
        short8 vf1 = *(const short8*)(vLds + ((rb + 64 + g4 * 16) ^ swz_m));
        o0[n] = __builtin_amdgcn_mfma_f32_16x16x32_bf16(pf00, vf0, o0[n], 0, 0, 0);
        o0[n] = __builtin_amdgcn_mfma_f32_16x16x32_bf16(pf01, vf1, o0[n], 0, 0, 0);
        o1[n] = __builtin_amdgcn_mfma_f32_16x16x32_bf16(pf10, vf0, o1[n], 0, 0, 0);
        o1[n] = __builtin_amdgcn_mfma_f32_16x16x32_bf16(pf11, vf1, o1[n], 0, 0, 0);
      }
      __builtin_amdgcn_s_setprio(0);
    }
    __syncthreads();
  }

  float inv0[4], inv1[4];
#pragma unroll
  for (int r = 0; r < 4; ++r) { inv0[r] = 1.f / lacc0[r]; inv1[r] = 1.f / lacc1[r]; }
  const size_t row0 = (size_t)b * SS + rbase + g4 * 4;
#pragma unroll
  for (int n = 0; n < 4; ++n)
#pragma unroll
    for (int r = 0; r < 4; ++r) {
      ao[(row0 + r) * (size_t)NQ + h * 64 + n * 16 + m16] = f2b(o0[n][r] * inv0[r]);
      ao[(row0 + 16 + r) * (size_t)NQ + h * 64 + n * 16 + m16] = f2b(o1[n][r] * inv1[r]);
    }
}

// ---- workspace layout (bytes) ----
constexpr size_t OFF_XB    = 0;                          // 11796480
constexpr size_t OFF_WQKVT = 11796480;                   // 29491200 (dead after QKV gemm -> p1)
constexpr size_t OFF_WOT   = OFF_WQKVT + 29491200;       // 3072*4096*2 = 25165824
constexpr size_t OFF_COS   = OFF_WOT + 25165824;         // 262144
constexpr size_t OFF_SIN   = OFF_COS + 262144;
constexpr size_t OFF_QKVF  = OFF_SIN + 262144;           // 41943040 (attnb=first 16.8MB; p0=tail 25.2MB)
constexpr size_t OFF_QB    = OFF_QKVF + 41943040;        // 16777216
constexpr size_t OFF_KB    = OFF_QB + 16777216;          // 2097152
constexpr size_t OFF_VTB   = OFF_KB + 2097152;           // 2097152

extern "C" void kernel_launch(void* const* d_in, const int* in_sizes, int n_in,
                              void* d_out, int out_size, void* d_ws, size_t ws_size,
                              hipStream_t stream) {
  const float* x  = (const float*)d_in[0];
  const float* wq = (const float*)d_in[1];
  const float* wk = (const float*)d_in[2];
  const float* wv = (const float*)d_in[3];
  const float* wo = (const float*)d_in[4];
  const int* pos  = (const int*)d_in[5];
  float* out = (float*)d_out;
  char* ws = (char*)d_ws;

  unsigned short* xb    = (unsigned short*)(ws + OFF_XB);
  unsigned short* wqkvt = (unsigned short*)(ws + OFF_WQKVT);
  unsigned short* wot   = (unsigned short*)(ws + OFF_WOT);
  float* ct             = (float*)(ws + OFF_COS);
  float* st             = (float*)(ws + OFF_SIN);
  float* qkvf           = (float*)(ws + OFF_QKVF);
  unsigned short* qbuf  = (unsigned short*)(ws + OFF_QB);
  unsigned short* kbuf  = (unsigned short*)(ws + OFF_KB);
  unsigned short* vtb   = (unsigned short*)(ws + OFF_VTB);
  unsigned short* attnb = (unsigned short*)(ws + OFF_QKVF);          // first 16.8MB of qkvf region
  float* p0             = (float*)(ws + OFF_QKVF + 16777216);        // tail 25.2MB of qkvf region
  float* p1             = (float*)(ws + OFF_WQKVT);                  // wqkvt dead after QKV gemm

  cast_x_kernel<<<(M_TOK * HIDDEN / 4 + 255) / 256, 256, 0, stream>>>(x, xb, M_TOK * HIDDEN / 4);
  rope_table<<<(M_TOK * 32) / 256, 256, 0, stream>>>(pos, ct, st);
  transpose_cast<<<dim3(NQ / 32, HIDDEN / 32), dim3(32, 8), 0, stream>>>(
      wq, NQ, wqkvt, HIDDEN, NQ);
  transpose_cast<<<dim3(NKVD / 32, HIDDEN / 32), dim3(32, 8), 0, stream>>>(
      wk, NKVD, wqkvt + (size_t)NQ * HIDDEN, HIDDEN, NKVD);
  transpose_cast<<<dim3(NKVD / 32, HIDDEN / 32), dim3(32, 8), 0, stream>>>(
      wv, NKVD, wqkvt + (size_t)(NQ + NKVD) * HIDDEN, HIDDEN, NKVD);
  transpose_cast<<<dim3(NOUT_PAD / 32, NQ / 32), dim3(32, 8), 0, stream>>>(
      wo, NOUT, wot, NQ, NOUT);
  // QKV projection: grid 20x8x1, K=2880
  gemm256<<<dim3(NQKV / 256, M_TOK / 256, 1), 512, 0, stream>>>(
      xb, wqkvt, qkvf, nullptr, HIDDEN, HIDDEN, NQKV, NQKV);
  rope_q_pack<<<(M_TOK * NH * 32) / 256, 256, 0, stream>>>(qkvf, ct, st, qbuf);
  rope_k_pack<<<(M_TOK * NKV * 32) / 256, 256, 0, stream>>>(qkvf, ct, st, kbuf);
  for (int b = 0; b < BB; ++b)
    transpose_cast<<<dim3(NKVD / 32, SS / 32), dim3(32, 8), 0, stream>>>(
        qkvf + (size_t)b * SS * NQKV + (NQ + NKVD), NQKV,
        vtb + (size_t)b * NKVD * SS, SS, NKVD);
  attn_fwd<<<dim3(4, BB * NH), 512, 0, stream>>>(qbuf, kbuf, vtb, attnb);
  // output projection: split-K=2 in grid z (192 concurrent blocks), partials fp32
  gemm256<<<dim3(NOUT_PAD / 256, M_TOK / 256, 2), 512, 0, stream>>>(
      attnb, wot, p0, p1, NQ, NQ / 2, NOUT_PAD, NOUT_PAD);
  reduce_wo<<<(M_TOK * 720) / 256, 256, 0, stream>>>(p0, p1, out);
}

// Round 6
// 293.062 us; speedup vs baseline: 1.2433x; 1.2433x over previous
//
#include <hip/hip_runtime.h>

// ---- problem constants ----
#define BB 2
#define SS 1024
#define HIDDEN 2880
#define NH 64
#define NKV 8
#define HD 64
#define M_TOK 2048          // B*S
#define NQ 4096             // NH*HD
#define NKVD 512            // NKV*HD
#define NQKV 5120           // NQ + 2*NKVD
#define NOUT 2880
#define NOUT_PAD 3072       // 12*256
#define PART_ELEMS 10485760 // 2048*5120 elements per QKV partial

typedef __attribute__((ext_vector_type(8))) short short8;
typedef __attribute__((ext_vector_type(4))) float f32x4;

__device__ __forceinline__ unsigned short f2b(float x) {
  union { float f; unsigned u; } v; v.f = x;
  unsigned r = (v.u + 0x7FFFu + ((v.u >> 16) & 1u)) >> 16;
  return (unsigned short)r;
}
__device__ __forceinline__ float b2f(unsigned short u) {
  union { unsigned u; float f; } v; v.u = ((unsigned)u) << 16; return v.f;
}

__device__ __forceinline__ void gload16(const void* g, void* l) {
  __builtin_amdgcn_global_load_lds(
      (const __attribute__((address_space(1))) void*)g,
      (__attribute__((address_space(3))) void*)l, 16, 0, 0);
}

#define BAR()  asm volatile("s_barrier" ::: "memory")
#define VMC0() asm volatile("s_waitcnt vmcnt(0)" ::: "memory")

// ---- cast x (fp32 -> bf16), vectorized ----
__global__ __launch_bounds__(256) void cast_x_kernel(const float* __restrict__ in,
                                                     unsigned short* __restrict__ out,
                                                     int n4) {
  int idx = blockIdx.x * 256 + threadIdx.x;
  if (idx >= n4) return;
  float4 v = ((const float4*)in)[idx];
  ushort4 o;
  o.x = f2b(v.x); o.y = f2b(v.y); o.z = f2b(v.z); o.w = f2b(v.w);
  ((ushort4*)out)[idx] = o;
}

// ---- transpose + cast (fp32 in): out[n*K + k] = (bf16) in[k*ldin + n] ----
__global__ __launch_bounds__(256) void transpose_cast(const float* __restrict__ in,
                                                      long ldin,
                                                      unsigned short* __restrict__ out,
                                                      int K, int N) {
  __shared__ float t[32][33];
  const int n0 = blockIdx.x * 32, k0 = blockIdx.y * 32;
  const int tx = threadIdx.x, ty = threadIdx.y;
#pragma unroll
  for (int i = 0; i < 4; ++i) {
    int k = k0 + ty + i * 8;
    int n = n0 + tx;
    t[ty + i * 8][tx] = (n < N) ? in[(long)k * ldin + n] : 0.f;
  }
  __syncthreads();
#pragma unroll
  for (int i = 0; i < 4; ++i) {
    int n = n0 + ty + i * 8;
    int k = k0 + tx;
    out[(long)n * K + k] = f2b(t[tx][ty + i * 8]);
  }
}

// ---- RoPE cos/sin table ----
__global__ __launch_bounds__(256) void rope_table(const int* __restrict__ pos,
                                                  float* __restrict__ ct,
                                                  float* __restrict__ st) {
  int tid = blockIdx.x * 256 + threadIdx.x;   // < 2048*32
  int t = tid >> 5, i = tid & 31;
  float p = (float)pos[t];
  float f = p * expf(-(float)i * (11.918390573078392f / 32.f));
  ct[tid] = cosf(f);
  st[tid] = sinf(f);
}

// ---- RoPE + pack q from 3 bf16 partials (pre-scaled by 1/8) ----
__global__ __launch_bounds__(256) void rope_q_pack3(const unsigned short* __restrict__ part,
                                                    const float* __restrict__ ct,
                                                    const float* __restrict__ st,
                                                    unsigned short* __restrict__ qb) {
  int tid = blockIdx.x * 256 + threadIdx.x;   // < 2048*64*32
  int i = tid & 31;
  int h = (tid >> 5) & 63;
  int t = tid >> 11;
  const unsigned short* sp = part + (size_t)t * NQKV + h * 64;
  float x1 = b2f(sp[i]) + b2f(sp[i + (size_t)PART_ELEMS]) + b2f(sp[i + 2 * (size_t)PART_ELEMS]);
  float x2 = b2f(sp[i + 32]) + b2f(sp[i + 32 + (size_t)PART_ELEMS]) + b2f(sp[i + 32 + 2 * (size_t)PART_ELEMS]);
  float c = ct[t * 32 + i], s = st[t * 32 + i];
  int b = t >> 10, sidx = t & 1023;
  unsigned short* dst = qb + (((size_t)(b * NH + h)) * SS + sidx) * HD;
  dst[i]      = f2b((x1 * c - x2 * s) * 0.125f);
  dst[i + 32] = f2b((x1 * s + x2 * c) * 0.125f);
}

// ---- RoPE + pack k from 3 bf16 partials ----
__global__ __launch_bounds__(256) void rope_k_pack3(const unsigned short* __restrict__ part,
                                                    const float* __restrict__ ct,
                                                    const float* __restrict__ st,
                                                    unsigned short* __restrict__ kb) {
  int tid = blockIdx.x * 256 + threadIdx.x;   // < 2048*8*32
  int i = tid & 31;
  int h = (tid >> 5) & 7;
  int t = tid >> 8;
  const unsigned short* sp = part + (size_t)t * NQKV + NQ + h * 64;
  float x1 = b2f(sp[i]) + b2f(sp[i + (size_t)PART_ELEMS]) + b2f(sp[i + 2 * (size_t)PART_ELEMS]);
  float x2 = b2f(sp[i + 32]) + b2f(sp[i + 32 + (size_t)PART_ELEMS]) + b2f(sp[i + 32 + 2 * (size_t)PART_ELEMS]);
  float c = ct[t * 32 + i], s = st[t * 32 + i];
  int b = t >> 10, sidx = t & 1023;
  unsigned short* dst = kb + (((size_t)(b * NKV + h)) * SS + sidx) * HD;
  dst[i]      = f2b(x1 * c - x2 * s);
  dst[i + 32] = f2b(x1 * s + x2 * c);
}

// ---- v pack: transpose + sum3: vtb[b][d][s] = sum_p part[p][b*1024+s][4608+d] ----
__global__ __launch_bounds__(256) void v_pack3(const unsigned short* __restrict__ part,
                                               unsigned short* __restrict__ vtb) {
  __shared__ float t[32][33];
  const int n0 = blockIdx.x * 32;              // d (0..511)
  const int b  = blockIdx.y >> 5;
  const int k0 = (blockIdx.y & 31) * 32;       // s (0..1023)
  const int tx = threadIdx.x, ty = threadIdx.y;
#pragma unroll
  for (int i = 0; i < 4; ++i) {
    int k = k0 + ty + i * 8;
    int n = n0 + tx;
    const unsigned short* sp = part + (size_t)(b * 1024 + k) * NQKV + (NQ + NKVD) + n;
    t[ty + i * 8][tx] = b2f(sp[0]) + b2f(sp[(size_t)PART_ELEMS]) + b2f(sp[2 * (size_t)PART_ELEMS]);
  }
  __syncthreads();
#pragma unroll
  for (int i = 0; i < 4; ++i) {
    int n = n0 + ty + i * 8;
    int k = k0 + tx;
    vtb[((size_t)(b * NKVD + n)) * SS + k] = f2b(t[tx][ty + i * 8]);
  }
}

// ==== GEMM 256x256, BK=64, 8 waves, T3-minimum schedule (1 vmcnt(0)+2 bar / tile) ====
// C(bf16) = A_bf16[M][lda] x Bt_bf16[N][lda]^T over Kloop cols starting at z*Kloop.
// grid z selects output partial C0/C1/C2. All next-tile stages go to buf^1 (never
// the buffer being read) -> race-free; single vmcnt(0) drains stage loads issued a
// full tile-body earlier (latency hidden); barrier gives cross-wave visibility.
__global__ __launch_bounds__(512, 2) void gemm256(const unsigned short* __restrict__ A,
                                                  const unsigned short* __restrict__ Bt,
                                                  unsigned short* __restrict__ C0,
                                                  unsigned short* __restrict__ C1,
                                                  unsigned short* __restrict__ C2,
                                                  int lda, int Kloop, int ldc, int Nvalid) {
  __shared__ short8 ldsA[2 * 2048];   // 2 bufs x 32KB
  __shared__ short8 ldsB[2 * 2048];
  char* lAc = (char*)ldsA;
  char* lBc = (char*)ldsB;
  const int tid = threadIdx.x;
  const int lane = tid & 63;
  const int w = tid >> 6;
  const int m16 = lane & 15, g4 = lane >> 4;
  const int wr = w >> 2;              // 0..1  (M wave-row)
  const int wc = w & 3;               // 0..3  (N wave-col)
  const int bm = blockIdx.y * 256, bn = blockIdx.x * 256;
  const int z = blockIdx.z;
  unsigned short* __restrict__ Cw = (z == 0) ? C0 : ((z == 1) ? C1 : C2);
  const size_t strAb = (size_t)lda * 2;            // row stride bytes
  const size_t koffb = (size_t)z * Kloop * 2;      // split-K byte offset
  const char* gAc = (const char*)A;
  const char* gBc = (const char*)Bt;

  // staging: 512 threads x 16B = 8KB = 64 rows x 128B per gload issue
  const int srow = tid >> 3;                                   // 0..63
  const int scolb = ((tid & 7) * 16) ^ ((srow & 7) << 4);      // inverse-swizzled src col
  const int sdst = w * 1024;                                   // wave-uniform dest

  auto stA = [&](int buf, int half, int kt) {
    const char* src = gAc + (size_t)(bm + half * 128 + srow) * strAb + koffb + (size_t)kt * 128 + scolb;
    char* dst = lAc + buf * 32768 + half * 16384 + sdst;
    gload16(src, dst);
    gload16(src + 64 * strAb, dst + 8192);
  };
  auto stB = [&](int buf, int half, int kt) {
    const char* src = gBc + (size_t)(bn + half * 128 + srow) * strAb + koffb + (size_t)kt * 128 + scolb;
    char* dst = lBc + buf * 32768 + half * 16384 + sdst;
    gload16(src, dst);
    gload16(src + 64 * strAb, dst + 8192);
  };

  // fragment reads (swizzled): global(row, kb) lives at LDS(row, kb ^ ((row&7)<<4))
  const int swz = (m16 & 7) << 4;
  const int kc0 = (g4 * 16) ^ swz;
  const int kc1 = (64 + g4 * 16) ^ swz;

  f32x4 acc[8][4];
#pragma unroll
  for (int i = 0; i < 8; ++i)
#pragma unroll
    for (int j = 0; j < 4; ++j) acc[i][j] = (f32x4){0.f, 0.f, 0.f, 0.f};
  short8 afr[4][2], bfr[2][2];

#define LOAD_A(bo, mh) { _Pragma("unroll") for (int mq = 0; mq < 4; ++mq) {                     \
    const int row = (mh) * 128 + wr * 64 + mq * 16 + m16;                                       \
    afr[mq][0] = *(const short8*)(lAc + (bo) + row * 128 + kc0);                                \
    afr[mq][1] = *(const short8*)(lAc + (bo) + row * 128 + kc1); } }
#define LOAD_B(bo, nh) { _Pragma("unroll") for (int nf = 0; nf < 2; ++nf) {                     \
    const int row = (nh) * 128 + wc * 32 + nf * 16 + m16;                                       \
    bfr[nf][0] = *(const short8*)(lBc + (bo) + row * 128 + kc0);                                \
    bfr[nf][1] = *(const short8*)(lBc + (bo) + row * 128 + kc1); } }
#define MFMA_Q(mh, nh) { __builtin_amdgcn_s_setprio(1);                                         \
  _Pragma("unroll") for (int mq = 0; mq < 4; ++mq)                                              \
  _Pragma("unroll") for (int nf = 0; nf < 2; ++nf) {                                            \
    acc[(mh)*4+mq][(nh)*2+nf] = __builtin_amdgcn_mfma_f32_16x16x32_bf16(                        \
        afr[mq][0], bfr[nf][0], acc[(mh)*4+mq][(nh)*2+nf], 0, 0, 0);                            \
    acc[(mh)*4+mq][(nh)*2+nf] = __builtin_amdgcn_mfma_f32_16x16x32_bf16(                        \
        afr[mq][1], bfr[nf][1], acc[(mh)*4+mq][(nh)*2+nf], 0, 0, 0); }                          \
  __builtin_amdgcn_s_setprio(0); }

  const int NT = Kloop >> 6;
  // prologue: stage tile0 into buf0 (8 loads), drain, sync
  stA(0, 0, 0); stB(0, 0, 0); stB(0, 1, 0); stA(0, 1, 0);
  VMC0();
  BAR();

  for (int t = 0; t < NT; ++t) {
    const int buf = t & 1;
    const int bo = buf * 32768;
    const int nb = buf ^ 1;
    if (t + 1 < NT) {   // stage ALL of tile t+1 now; lands while we compute tile t
      stA(nb, 0, t + 1); stB(nb, 0, t + 1);
      stB(nb, 1, t + 1); stA(nb, 1, t + 1);
    }
    // half 1: quadrants (0,0), (0,1)
    LOAD_A(bo, 0);
    LOAD_B(bo, 0);
    MFMA_Q(0, 0);
    LOAD_B(bo, 1);
    MFMA_Q(0, 1);
    BAR();   // scope fence (no data hazard): bounds hoisting + wave drift
    // half 2: quadrants (1,1), (1,0)
    LOAD_A(bo, 1);
    MFMA_Q(1, 1);
    LOAD_B(bo, 0);
    MFMA_Q(1, 0);
    VMC0();  // stages issued at tile top have had a full tile body to land
    BAR();
  }
#undef LOAD_A
#undef LOAD_B
#undef MFMA_Q

  // epilogue (bf16): row = bm + mh*128 + wr*64 + mq*16 + g4*4 + r ; col = bn + nh*128 + wc*32 + nf*16 + m16
#pragma unroll
  for (int mi = 0; mi < 8; ++mi) {
    const int mh = mi >> 2, mq = mi & 3;
    const size_t row = bm + mh * 128 + wr * 64 + mq * 16 + g4 * 4;
#pragma unroll
    for (int ni = 0; ni < 4; ++ni) {
      const int nh = ni >> 1, nf = ni & 1;
      const int col = bn + nh * 128 + wc * 32 + nf * 16 + m16;
      if (col < Nvalid) {
#pragma unroll
        for (int r = 0; r < 4; ++r)
          Cw[(row + r) * (size_t)ldc + col] = f2b(acc[mi][ni][r]);
      }
    }
  }
}

// ---- split-K reduce: out[2048][2880] fp32 = p0 + p1 (bf16 [2048][3072]) ----
__global__ __launch_bounds__(256) void reduce_wo(const unsigned short* __restrict__ p0,
                                                 const unsigned short* __restrict__ p1,
                                                 float* __restrict__ out) {
  int idx = blockIdx.x * 256 + threadIdx.x;   // < 2048*720
  int row = idx / 720, c4 = idx - row * 720;
  const ushort4 a = *(const ushort4*)(p0 + (size_t)row * 3072 + c4 * 4);
  const ushort4 b = *(const ushort4*)(p1 + (size_t)row * 3072 + c4 * 4);
  float4 o;
  o.x = b2f(a.x) + b2f(b.x);
  o.y = b2f(a.y) + b2f(b.y);
  o.z = b2f(a.z) + b2f(b.z);
  o.w = b2f(a.w) + b2f(b.w);
  *(float4*)(out + (size_t)row * 2880 + c4 * 4) = o;
}

// ---- flash attention (unchanged, validated R2-R5) ----
__global__ __launch_bounds__(512) void attn_fwd(const unsigned short* __restrict__ qb,
                                                const unsigned short* __restrict__ kb,
                                                const unsigned short* __restrict__ vtb,
                                                unsigned short* __restrict__ ao) {
  __shared__ unsigned short kB[2][64 * 64];
  __shared__ unsigned short vB[2][64 * 64];
  __shared__ unsigned short pB[8][32 * 64];
  const int tid = threadIdx.x, lane = tid & 63, w = tid >> 6;
  const int qblk = blockIdx.x;
  const int bh = blockIdx.y;
  const int b = bh >> 6, h = bh & 63, hkv = h >> 3;
  const int m16 = lane & 15, g4 = lane >> 4;
  const int rbase = qblk * 256 + w * 32;

  const unsigned short* qp =
      qb + (((size_t)(b * NH + h)) * SS + rbase + m16) * HD + g4 * 8;
  const short8 q00 = *(const short8*)(qp);
  const short8 q01 = *(const short8*)(qp + 32);
  const short8 q10 = *(const short8*)(qp + 16 * HD);
  const short8 q11 = *(const short8*)(qp + 16 * HD + 32);

  const char* kbp = (const char*)(kb + ((size_t)(b * NKV + hkv)) * SS * HD);
  const char* vbp = (const char*)(vtb + ((size_t)(b * NKV + hkv)) * HD * SS);

  const int lrow = lane >> 3;
  const int lcolb = ((lane & 7) * 16) ^ ((lrow & 7) << 4);
  unsigned short* kDst0 = &kB[0][w * 512];
  unsigned short* kDst1 = &kB[1][w * 512];
  unsigned short* vDst0 = &vB[0][w * 512];
  unsigned short* vDst1 = &vB[1][w * 512];
  const size_t kRowOff = (size_t)(w * 8 + lrow) * 128 + lcolb;
  const size_t vRowOff = (size_t)(w * 8 + lrow) * 2048 + lcolb;

  const short8 ones = {(short)0x3F80, (short)0x3F80, (short)0x3F80, (short)0x3F80,
                       (short)0x3F80, (short)0x3F80, (short)0x3F80, (short)0x3F80};

  f32x4 o0[4], o1[4];
#pragma unroll
  for (int n = 0; n < 4; ++n) { o0[n] = (f32x4){0,0,0,0}; o1[n] = (f32x4){0,0,0,0}; }
  f32x4 lacc0 = (f32x4){0,0,0,0}, lacc1 = (f32x4){0,0,0,0};
  float mrow0[4] = {-1e30f,-1e30f,-1e30f,-1e30f};
  float mrow1[4] = {-1e30f,-1e30f,-1e30f,-1e30f};

  char* pw = (char*)pB[w];
  const int swz_m = (m16 & 7) << 4;
  const int nt = (qblk + 1) * 4;

  gload16(kbp + kRowOff, kDst0);
  gload16(vbp + vRowOff, vDst0);
  __syncthreads();

  for (int t = 0; t < nt; ++t) {
    const int k0 = t * 64;
    const char* kLds = (const char*)kB[t & 1];
    const char* vLds = (const char*)vB[t & 1];
    if (t + 1 < nt) {
      if (t & 1) { gload16(kbp + (size_t)(t + 1) * 8192 + kRowOff, kDst0);
                   gload16(vbp + (size_t)(t + 1) * 128  + vRowOff, vDst0); }
      else       { gload16(kbp + (size_t)(t + 1) * 8192 + kRowOff, kDst1);
                   gload16(vbp + (size_t)(t + 1) * 128  + vRowOff, vDst1); }
    }
    if (k0 < rbase + 32) {
      short8 kf0[4], kf1[4];
#pragma unroll
      for (int kf = 0; kf < 4; ++kf) {
        const int rb = (kf * 16 + m16) * 128;
        kf0[kf] = *(const short8*)(kLds + ((rb + g4 * 16) ^ swz_m));
        kf1[kf] = *(const short8*)(kLds + ((rb + 64 + g4 * 16) ^ swz_m));
      }
      f32x4 s0[4], s1[4];
      __builtin_amdgcn_s_setprio(1);
#pragma unroll
      for (int kf = 0; kf < 4; ++kf) {
        f32x4 z = (f32x4){0,0,0,0};
        z = __builtin_amdgcn_mfma_f32_16x16x32_bf16(q00, kf0[kf], z, 0, 0, 0);
        z = __builtin_amdgcn_mfma_f32_16x16x32_bf16(q01, kf1[kf], z, 0, 0, 0);
        s0[kf] = z;
        f32x4 z2 = (f32x4){0,0,0,0};
        z2 = __builtin_amdgcn_mfma_f32_16x16x32_bf16(q10, kf0[kf], z2, 0, 0, 0);
        z2 = __builtin_amdgcn_mfma_f32_16x16x32_bf16(q11, kf1[kf], z2, 0, 0, 0);
        s1[kf] = z2;
      }
      __builtin_amdgcn_s_setprio(0);
      if (k0 + 63 >= rbase) {
#pragma unroll
        for (int kf = 0; kf < 4; ++kf)
#pragma unroll
          for (int r = 0; r < 4; ++r) {
            const int col = k0 + kf * 16 + m16;
            if (col > rbase + g4 * 4 + r)      s0[kf][r] = -1e30f;
            if (col > rbase + 16 + g4 * 4 + r) s1[kf][r] = -1e30f;
          }
      }
      int grow = 0;
#pragma unroll
      for (int kf = 0; kf < 4; ++kf)
#pragma unroll
        for (int r = 0; r < 4; ++r) {
          grow |= (s0[kf][r] > mrow0[r] + 8.f);
          grow |= (s1[kf][r] > mrow1[r] + 8.f);
        }
      if (__any(grow)) {
        float mx0[4], mx1[4];
#pragma unroll
        for (int r = 0; r < 4; ++r) {
          mx0[r] = fmaxf(fmaxf(s0[0][r], s0[1][r]), fmaxf(s0[2][r], s0[3][r]));
          mx1[r] = fmaxf(fmaxf(s1[0][r], s1[1][r]), fmaxf(s1[2][r], s1[3][r]));
        }
#pragma unroll
        for (int off = 1; off <= 8; off <<= 1)
#pragma unroll
          for (int r = 0; r < 4; ++r) {
            mx0[r] = fmaxf(mx0[r], __shfl_xor(mx0[r], off));
            mx1[r] = fmaxf(mx1[r], __shfl_xor(mx1[r], off));
          }
#pragma unroll
        for (int r = 0; r < 4; ++r) {
          float mn0 = fmaxf(mrow0[r], mx0[r]);
          float sc0 = __expf(mrow0[r] - mn0);
          mrow0[r] = mn0; lacc0[r] *= sc0;
          float mn1 = fmaxf(mrow1[r], mx1[r]);
          float sc1 = __expf(mrow1[r] - mn1);
          mrow1[r] = mn1; lacc1[r] *= sc1;
#pragma unroll
          for (int n = 0; n < 4; ++n) { o0[n][r] *= sc0; o1[n][r] *= sc1; }
        }
      }
#pragma unroll
      for (int kf = 0; kf < 4; ++kf)
#pragma unroll
        for (int r = 0; r < 4; ++r) {
          const int colb = (kf * 16 + m16) * 2;
          int row = g4 * 4 + r;
          *(unsigned short*)(pw + ((row * 128 + colb) ^ ((row & 7) << 4))) =
              f2b(__expf(s0[kf][r] - mrow0[r]));
          row += 16;
          *(unsigned short*)(pw + ((row * 128 + colb) ^ ((row & 7) << 4))) =
              f2b(__expf(s1[kf][r] - mrow1[r]));
        }
      const int prb0 = m16 * 128, prb1 = (16 + m16) * 128;
      short8 pf00 = *(const short8*)(pw + ((prb0 + g4 * 16) ^ swz_m));
      short8 pf01 = *(const short8*)(pw + ((prb0 + 64 + g4 * 16) ^ swz_m));
      short8 pf10 = *(const short8*)(pw + ((prb1 + g4 * 16) ^ swz_m));
      short8 pf11 = *(const short8*)(pw + ((prb1 + 64 + g4 * 16) ^ swz_m));
      __builtin_amdgcn_s_setprio(1);
      lacc0 = __builtin_amdgcn_mfma_f32_16x16x32_bf16(pf00, ones, lacc0, 0, 0, 0);
      lacc0 = __builtin_amdgcn_mfma_f32_16x16x32_bf16(pf01, ones, lacc0, 0, 0, 0);
      lacc1 = __builtin_amdgcn_mfma_f32_16x16x32_bf16(pf10, ones, lacc1, 0, 0, 0);
      lacc1 = __builtin_amdgcn_mfma_f32_16x16x32_bf16(pf11, ones, lacc1, 0, 0, 0);
#pragma unroll
      for (int n = 0; n < 4; ++n) {
        const int rb = (n * 16 + m16) * 128;
        short8 vf0 = *(const short8*)(vLds + ((rb + g4 * 16) ^ swz_m));
        short8 vf1 = *(const short8*)(vLds + ((rb + 64 + g4 * 16) ^ swz_m));
        o0[n] = __builtin_amdgcn_mfma_f32_16x16x32_bf16(pf00, vf0, o0[n], 0, 0, 0);
        o0[n] = __builtin_amdgcn_mfma_f32_16x16x32_bf16(pf01, vf1, o0[n], 0, 0, 0);
        o1[n] = __builtin_amdgcn_mfma_f32_16x16x32_bf16(pf10, vf0, o1[n], 0, 0, 0);
        o1[n] = __builtin_amdgcn_mfma_f32_16x16x32_bf16(pf11, vf1, o1[n], 0, 0, 0);
      }
      __builtin_amdgcn_s_setprio(0);
    }
    __syncthreads();
  }

  float inv0[4], inv1[4];
#pragma unroll
  for (int r = 0; r < 4; ++r) { inv0[r] = 1.f / lacc0[r]; inv1[r] = 1.f / lacc1[r]; }
  const size_t row0 = (size_t)b * SS + rbase + g4 * 4;
#pragma unroll
  for (int n = 0; n < 4; ++n)
#pragma unroll
    for (int r = 0; r < 4; ++r) {
      ao[(row0 + r) * (size_t)NQ + h * 64 + n * 16 + m16] = f2b(o0[n][r] * inv0[r]);
      ao[(row0 + 16 + r) * (size_t)NQ + h * 64 + n * 16 + m16] = f2b(o1[n][r] * inv1[r]);
    }
}

// ---- workspace layout (bytes), total 125,698,048 (< 129.8MB proven) ----
// Region A (0..41,287,680):   xb(11.8M)+wqkvt(29.5M)  [live thru QKV gemm]
//   then: wot bf16 [3072][4096] @0 (25.2M); p1 bf16 [2048][3072] @25,165,824 (12.6M)
// Region B (41,287,680..104,202,240): QKV partials bf16 [3][2048][5120] (62.9M)
//   then: attnb bf16 [2048][4096] @41,287,680 (16.8M); p0 @58,064,896 (12.6M)
constexpr size_t OFF_XB    = 0;
constexpr size_t OFF_WQKVT = 11796480;
constexpr size_t OFF_PART  = 41287680;
constexpr size_t OFF_WOT   = 0;
constexpr size_t OFF_P1    = 25165824;
constexpr size_t OFF_ATTNB = 41287680;
constexpr size_t OFF_P0    = 58064896;
constexpr size_t OFF_CT    = 104202240;
constexpr size_t OFF_ST    = 104464384;
constexpr size_t OFF_QB    = 104726528;
constexpr size_t OFF_KB    = 121503744;
constexpr size_t OFF_VTB   = 123600896;

extern "C" void kernel_launch(void* const* d_in, const int* in_sizes, int n_in,
                              void* d_out, int out_size, void* d_ws, size_t ws_size,
                              hipStream_t stream) {
  const float* x  = (const float*)d_in[0];
  const float* wq = (const float*)d_in[1];
  const float* wk = (const float*)d_in[2];
  const float* wv = (const float*)d_in[3];
  const float* wo = (const float*)d_in[4];
  const int* pos  = (const int*)d_in[5];
  float* out = (float*)d_out;
  char* ws = (char*)d_ws;

  unsigned short* xb    = (unsigned short*)(ws + OFF_XB);
  unsigned short* wqkvt = (unsigned short*)(ws + OFF_WQKVT);
  unsigned short* part  = (unsigned short*)(ws + OFF_PART);
  unsigned short* wot   = (unsigned short*)(ws + OFF_WOT);
  unsigned short* p1    = (unsigned short*)(ws + OFF_P1);
  unsigned short* attnb = (unsigned short*)(ws + OFF_ATTNB);
  unsigned short* p0    = (unsigned short*)(ws + OFF_P0);
  float* ct             = (float*)(ws + OFF_CT);
  float* st             = (float*)(ws + OFF_ST);
  unsigned short* qbuf  = (unsigned short*)(ws + OFF_QB);
  unsigned short* kbuf  = (unsigned short*)(ws + OFF_KB);
  unsigned short* vtb   = (unsigned short*)(ws + OFF_VTB);

  cast_x_kernel<<<(M_TOK * HIDDEN / 4 + 255) / 256, 256, 0, stream>>>(x, xb, M_TOK * HIDDEN / 4);
  rope_table<<<(M_TOK * 32) / 256, 256, 0, stream>>>(pos, ct, st);
  transpose_cast<<<dim3(NQ / 32, HIDDEN / 32), dim3(32, 8), 0, stream>>>(
      wq, NQ, wqkvt, HIDDEN, NQ);
  transpose_cast<<<dim3(NKVD / 32, HIDDEN / 32), dim3(32, 8), 0, stream>>>(
      wk, NKVD, wqkvt + (size_t)NQ * HIDDEN, HIDDEN, NKVD);
  transpose_cast<<<dim3(NKVD / 32, HIDDEN / 32), dim3(32, 8), 0, stream>>>(
      wv, NKVD, wqkvt + (size_t)(NQ + NKVD) * HIDDEN, HIDDEN, NKVD);
  // QKV projection: split-K=3 (K=3x960), grid 20x8x3 = 480 blocks, bf16 partials
  gemm256<<<dim3(NQKV / 256, M_TOK / 256, 3), 512, 0, stream>>>(
      xb, wqkvt, part, part + (size_t)PART_ELEMS, part + 2 * (size_t)PART_ELEMS,
      HIDDEN, HIDDEN / 3, NQKV, NQKV);
  // wo transpose into region A (xb/wqkvt now dead)
  transpose_cast<<<dim3(NOUT_PAD / 32, NQ / 32), dim3(32, 8), 0, stream>>>(
      wo, NOUT, wot, NQ, NOUT);
  // RoPE + pack (sums the 3 partials)
  rope_q_pack3<<<(M_TOK * NH * 32) / 256, 256, 0, stream>>>(part, ct, st, qbuf);
  rope_k_pack3<<<(M_TOK * NKV * 32) / 256, 256, 0, stream>>>(part, ct, st, kbuf);
  v_pack3<<<dim3(NKVD / 32, BB * 32), dim3(32, 8), 0, stream>>>(part, vtb);
  // attention (partials dead; attnb overlays part[0])
  attn_fwd<<<dim3(4, BB * NH), 512, 0, stream>>>(qbuf, kbuf, vtb, attnb);
  // output projection: split-K=2 (K=2x2048), grid 12x8x2 = 192 blocks, bf16 partials
  gemm256<<<dim3(NOUT_PAD / 256, M_TOK / 256, 2), 512, 0, stream>>>(
      attnb, wot, p0, p1, nullptr, NQ, NQ / 2, NOUT_PAD, NOUT_PAD);
  reduce_wo<<<(M_TOK * 720) / 256, 256, 0, stream>>>(p0, p1, out);
}